// Round 1
// baseline (285.264 us; speedup 1.0000x reference)
//
#include <hip/hip_runtime.h>

// ModePool2d: K=2, S=2, P=0, NBINS=17
// x: (16, 64, 224, 224) fp32  ->  out: (16, 64, 112, 112) fp32
// bin = clip(rint(x*16), 0, 16); out = mode(4 bins, tie -> smallest bin) / 16

#define IN_H 224
#define IN_W 224
#define OUT_H 112
#define OUT_W 112
#define BC_TOTAL (16 * 64)

__device__ __forceinline__ int binq(float x) {
    // jnp.round = round-half-to-even -> rintf (default rounding mode = RNE)
    float r = rintf(x * 16.0f);
    r = fminf(fmaxf(r, 0.0f), 16.0f);
    return (int)r;
}

__device__ __forceinline__ int mode4(int b0, int b1, int b2, int b3) {
    int c0 = (b0 == b1) + (b0 == b2) + (b0 == b3);
    int c1 = (b1 == b0) + (b1 == b2) + (b1 == b3);
    int c2 = (b2 == b0) + (b2 == b1) + (b2 == b3);
    int c3 = (b3 == b0) + (b3 == b1) + (b3 == b2);
    // maximize count; tie-break -> smaller bin value (reference scans v ascending
    // with strict '>'). score = count*32 - bin is unique per distinct bin.
    int s0 = c0 * 32 - b0;
    int s1 = c1 * 32 - b1;
    int s2 = c2 * 32 - b2;
    int s3 = c3 * 32 - b3;
    int sb = s0, bb = b0;
    if (s1 > sb) { sb = s1; bb = b1; }
    if (s2 > sb) { sb = s2; bb = b2; }
    if (s3 > sb) { sb = s3; bb = b3; }
    return bb;
}

__global__ __launch_bounds__(256) void ModePool2d_kernel(
        const float* __restrict__ x, float* __restrict__ out) {
    // one thread = 2 adjacent output pixels (one float4 per input row)
    int tid = blockIdx.x * 256 + threadIdx.x;   // 0 .. 16*64*112*56-1 (exact)
    int wp = tid % (OUT_W / 2);                 // which float4 within the row
    int t  = tid / (OUT_W / 2);
    int ho = t % OUT_H;
    int bc = t / OUT_H;

    const float* base = x + (size_t)bc * (IN_H * IN_W) + (size_t)(2 * ho) * IN_W;
    float4 r0 = ((const float4*)base)[wp];            // row 2h,   cols 4wp..4wp+3
    float4 r1 = ((const float4*)(base + IN_W))[wp];   // row 2h+1, cols 4wp..4wp+3

    int a0 = binq(r0.x), a1 = binq(r0.y), a2 = binq(r0.z), a3 = binq(r0.w);
    int b0 = binq(r1.x), b1 = binq(r1.y), b2 = binq(r1.z), b3 = binq(r1.w);

    float o0 = (float)mode4(a0, a1, b0, b1) * 0.0625f;
    float o1 = (float)mode4(a2, a3, b2, b3) * 0.0625f;

    float2* o = (float2*)(out + (size_t)bc * (OUT_H * OUT_W)
                              + (size_t)ho * OUT_W + 2 * wp);
    *o = make_float2(o0, o1);
}

extern "C" void kernel_launch(void* const* d_in, const int* in_sizes, int n_in,
                              void* d_out, int out_size, void* d_ws, size_t ws_size,
                              hipStream_t stream) {
    const float* x = (const float*)d_in[0];
    float* out = (float*)d_out;
    // total thread count: 16*64*112*(112/2) = 6,422,528 = 25088 * 256 (exact)
    const int total_threads = BC_TOTAL * OUT_H * (OUT_W / 2);
    const int block = 256;
    const int grid = total_threads / block;
    ModePool2d_kernel<<<grid, block, 0, stream>>>(x, out);
}

// Round 3
// 273.530 us; speedup vs baseline: 1.0429x; 1.0429x over previous
//
#include <hip/hip_runtime.h>

// ModePool2d: K=2, S=2, P=0, NBINS=17
// x: (16, 64, 224, 224) fp32  ->  out: (16, 64, 112, 112) fp32
// bin = clip(rint(x*16), 0, 16); out = mode(4 bins, tie -> smallest bin) / 16
//
// Streaming, HBM-bound: 205 MB read + 51 MB write ~= 38-41 us floor @ 6.7 TB/s.
// Each thread: 8x2 input patch (4x 16B loads) -> 4 outputs (1x 16B store).

#define IN_H 224
#define IN_W 224
#define OUT_H 112
#define OUT_W 112
#define BC_TOTAL (16 * 64)

// native clang vector type: __builtin_nontemporal_* requires scalar/native-vector,
// not HIP_vector_type structs
typedef float vf4 __attribute__((ext_vector_type(4)));

__device__ __forceinline__ int binq(float x) {
    // jnp.round = round-half-to-even -> rintf (default mode = RNE)
    float r = rintf(x * 16.0f);
    r = fminf(fmaxf(r, 0.0f), 16.0f);
    return (int)r;
}

__device__ __forceinline__ float mode4f(int b0, int b1, int b2, int b3) {
    int c0 = (b0 == b1) + (b0 == b2) + (b0 == b3);
    int c1 = (b1 == b0) + (b1 == b2) + (b1 == b3);
    int c2 = (b2 == b0) + (b2 == b1) + (b2 == b3);
    int c3 = (b3 == b0) + (b3 == b1) + (b3 == b2);
    // maximize count; tie-break -> smaller bin (ref scans v ascending, strict '>')
    int s0 = c0 * 32 - b0;
    int s1 = c1 * 32 - b1;
    int s2 = c2 * 32 - b2;
    int s3 = c3 * 32 - b3;
    int sb = s0, bb = b0;
    if (s1 > sb) { sb = s1; bb = b1; }
    if (s2 > sb) { sb = s2; bb = b2; }
    if (s3 > sb) { sb = s3; bb = b3; }
    return (float)bb * 0.0625f;
}

__global__ __launch_bounds__(256) void ModePool2d_kernel(
        const float* __restrict__ x, float* __restrict__ out) {
    // one thread = 4 adjacent output pixels (8-wide x 2-row input patch)
    int tid = blockIdx.x * 256 + threadIdx.x;   // 0 .. 16*64*112*28-1 (exact)
    int qp = tid % (OUT_W / 4);                 // which float4-out within the row
    int t  = tid / (OUT_W / 4);
    int ho = t % OUT_H;
    int bc = t / OUT_H;

    const float* base = x + (size_t)bc * (IN_H * IN_W)
                          + (size_t)(2 * ho) * IN_W + 8 * qp;
    const vf4* p0 = (const vf4*)base;           // row 2h
    const vf4* p1 = (const vf4*)(base + IN_W);  // row 2h+1
    vf4 r00 = __builtin_nontemporal_load(p0);
    vf4 r01 = __builtin_nontemporal_load(p0 + 1);
    vf4 r10 = __builtin_nontemporal_load(p1);
    vf4 r11 = __builtin_nontemporal_load(p1 + 1);

    int a0 = binq(r00.x), a1 = binq(r00.y), a2 = binq(r00.z), a3 = binq(r00.w);
    int a4 = binq(r01.x), a5 = binq(r01.y), a6 = binq(r01.z), a7 = binq(r01.w);
    int b0 = binq(r10.x), b1 = binq(r10.y), b2 = binq(r10.z), b3 = binq(r10.w);
    int b4 = binq(r11.x), b5 = binq(r11.y), b6 = binq(r11.z), b7 = binq(r11.w);

    vf4 o;
    o.x = mode4f(a0, a1, b0, b1);
    o.y = mode4f(a2, a3, b2, b3);
    o.z = mode4f(a4, a5, b4, b5);
    o.w = mode4f(a6, a7, b6, b7);

    vf4* op = (vf4*)(out + (size_t)bc * (OUT_H * OUT_W)
                         + (size_t)ho * OUT_W + 4 * qp);
    __builtin_nontemporal_store(o, op);
}

extern "C" void kernel_launch(void* const* d_in, const int* in_sizes, int n_in,
                              void* d_out, int out_size, void* d_ws, size_t ws_size,
                              hipStream_t stream) {
    const float* x = (const float*)d_in[0];
    float* out = (float*)d_out;
    // total threads: 16*64*112*(112/4) = 3,211,264 = 12544 * 256 (exact)
    const int total_threads = BC_TOTAL * OUT_H * (OUT_W / 4);
    const int block = 256;
    const int grid = total_threads / block;
    ModePool2d_kernel<<<grid, block, 0, stream>>>(x, out);
}